// Round 2
// baseline (10604.296 us; speedup 1.0000x reference)
//
#include <hip/hip_runtime.h>

#define NC_N 100000
#define NV_N 100000
#define E_N  3200000

// c = relu(cons_features @ Wc + bc) : [NC,2] -> f32 table [NC,32]
__global__ __launch_bounds__(256) void k_embed_cons(
    const float* __restrict__ f, const float* __restrict__ W,
    const float* __restrict__ b, float* __restrict__ out)
{
    int n = blockIdx.x * blockDim.x + threadIdx.x;
    if (n >= NC_N) return;
    float f0 = f[2*(size_t)n], f1 = f[2*(size_t)n + 1];
    float4* dst = (float4*)(out + (size_t)n * 32);
    #pragma unroll
    for (int q = 0; q < 8; q++){
        float4 r;
        #pragma unroll
        for (int j = 0; j < 4; j++){
            int o = q*4 + j;
            (&r.x)[j] = fmaxf(fmaf(f0, W[o], fmaf(f1, W[32 + o], b[o])), 0.f);
        }
        dst[q] = r;
    }
}

// v = relu(vars_features @ Wv + bv) : [NV,9] -> f32 table [NV,32]
__global__ __launch_bounds__(256) void k_embed_vars(
    const float* __restrict__ f, const float* __restrict__ W,
    const float* __restrict__ b, float* __restrict__ out)
{
    int n = blockIdx.x * blockDim.x + threadIdx.x;
    if (n >= NV_N) return;
    float x[9];
    #pragma unroll
    for (int k = 0; k < 9; k++) x[k] = f[9*(size_t)n + k];
    float4* dst = (float4*)(out + (size_t)n * 32);
    #pragma unroll
    for (int q = 0; q < 8; q++){
        float4 r;
        #pragma unroll
        for (int j = 0; j < 4; j++){
            int o = q*4 + j;
            float s = b[o];
            #pragma unroll
            for (int k = 0; k < 9; k++) s = fmaf(x[k], W[k*32 + o], s);
            (&r.x)[j] = fmaxf(s, 0.f);
        }
        dst[q] = r;
    }
}

// One thread per edge: x = [A[ia], V[ib]] (64) -> relu(x@W1+b1) -> relu(@W2+b2)
// -> atomicAdd into acc[target]. scatter_b=0 -> target=ia (pass1), 1 -> ib (pass2).
__global__ __launch_bounds__(256) void k_edge(
    const float* __restrict__ A, const float* __restrict__ V,
    const int* __restrict__ eA, const int* __restrict__ eV,
    const float* __restrict__ W1, const float* __restrict__ b1,
    const float* __restrict__ W2, const float* __restrict__ b2,
    float* __restrict__ acc, int scatter_b)
{
    int e = blockIdx.x * blockDim.x + threadIdx.x;
    if (e >= E_N) return;
    int ia = eA[e], ib = eV[e];
    const float4* ap = (const float4*)(A + (size_t)ia * 32);
    const float4* vp = (const float4*)(V + (size_t)ib * 32);

    float h[32];
    #pragma unroll
    for (int o = 0; o < 32; o++) h[o] = b1[o];
    #pragma unroll
    for (int q = 0; q < 8; q++){
        float4 t = ap[q];
        #pragma unroll
        for (int j = 0; j < 4; j++){
            float xk = (&t.x)[j];
            const float* w = W1 + (q*4 + j)*32;
            #pragma unroll
            for (int o = 0; o < 32; o++) h[o] = fmaf(xk, w[o], h[o]);
        }
    }
    #pragma unroll
    for (int q = 0; q < 8; q++){
        float4 t = vp[q];
        #pragma unroll
        for (int j = 0; j < 4; j++){
            float xk = (&t.x)[j];
            const float* w = W1 + (32 + q*4 + j)*32;
            #pragma unroll
            for (int o = 0; o < 32; o++) h[o] = fmaf(xk, w[o], h[o]);
        }
    }
    #pragma unroll
    for (int o = 0; o < 32; o++) h[o] = fmaxf(h[o], 0.f);

    float g[32];
    #pragma unroll
    for (int o = 0; o < 32; o++) g[o] = b2[o];
    #pragma unroll
    for (int k = 0; k < 32; k++){
        float hk = h[k];
        const float* w = W2 + k*32;
        #pragma unroll
        for (int o = 0; o < 32; o++) g[o] = fmaf(hk, w[o], g[o]);
    }

    int tgt = scatter_b ? ib : ia;
    float* dst = acc + (size_t)tgt * 32;
    #pragma unroll
    for (int o = 0; o < 32; o++) unsafeAtomicAdd(dst + o, fmaxf(g[o], 0.f));
}

// out_c = relu(concat(acc, c) @ Wcr + bcr), written IN PLACE over c table
// (row-elementwise: each thread reads its own row before writing it).
__global__ __launch_bounds__(256) void k_consrep(
    const float* __restrict__ acc, float* __restrict__ cemb,
    const float* __restrict__ W, const float* __restrict__ b)
{
    int n = blockIdx.x * blockDim.x + threadIdx.x;
    if (n >= NC_N) return;
    float x[64];
    const float4* ap = (const float4*)(acc + (size_t)n * 32);
    const float4* cp = (const float4*)(cemb + (size_t)n * 32);
    #pragma unroll
    for (int q = 0; q < 8; q++){
        float4 t = ap[q];
        x[q*4+0]=t.x; x[q*4+1]=t.y; x[q*4+2]=t.z; x[q*4+3]=t.w;
    }
    #pragma unroll
    for (int q = 0; q < 8; q++){
        float4 t = cp[q];
        x[32+q*4+0]=t.x; x[32+q*4+1]=t.y; x[32+q*4+2]=t.z; x[32+q*4+3]=t.w;
    }
    float h[32];
    #pragma unroll
    for (int o = 0; o < 32; o++) h[o] = b[o];
    #pragma unroll
    for (int k = 0; k < 64; k++){
        float xk = x[k];
        const float* w = W + k*32;
        #pragma unroll
        for (int o = 0; o < 32; o++) h[o] = fmaf(xk, w[o], h[o]);
    }
    float4* dst = (float4*)(cemb + (size_t)n * 32);
    #pragma unroll
    for (int q = 0; q < 8; q++){
        float4 r;
        #pragma unroll
        for (int j = 0; j < 4; j++) (&r.x)[j] = fmaxf(h[q*4 + j], 0.f);
        dst[q] = r;
    }
}

// out_v = relu(concat(acc, v) @ Wvr+bvr); relu(@Wo1); relu(@Wo2); @Wo3+bo3 -> [NV,1]
__global__ __launch_bounds__(256) void k_out(
    const float* __restrict__ acc, const float* __restrict__ vemb,
    const float* __restrict__ Wvr, const float* __restrict__ bvr,
    const float* __restrict__ Wo1, const float* __restrict__ bo1,
    const float* __restrict__ Wo2, const float* __restrict__ bo2,
    const float* __restrict__ Wo3, const float* __restrict__ bo3,
    float* __restrict__ out)
{
    int n = blockIdx.x * blockDim.x + threadIdx.x;
    if (n >= NV_N) return;
    float a[32];
    #pragma unroll
    for (int o = 0; o < 32; o++) a[o] = bvr[o];
    const float4* ap = (const float4*)(acc + (size_t)n * 32);
    #pragma unroll
    for (int q = 0; q < 8; q++){
        float4 t = ap[q];
        #pragma unroll
        for (int j = 0; j < 4; j++){
            float xk = (&t.x)[j];
            const float* w = Wvr + (q*4 + j)*32;
            #pragma unroll
            for (int o = 0; o < 32; o++) a[o] = fmaf(xk, w[o], a[o]);
        }
    }
    const float4* vp = (const float4*)(vemb + (size_t)n * 32);
    #pragma unroll
    for (int q = 0; q < 8; q++){
        float4 t = vp[q];
        #pragma unroll
        for (int j = 0; j < 4; j++){
            float xk = (&t.x)[j];
            const float* w = Wvr + (32 + q*4 + j)*32;
            #pragma unroll
            for (int o = 0; o < 32; o++) a[o] = fmaf(xk, w[o], a[o]);
        }
    }
    #pragma unroll
    for (int o = 0; o < 32; o++) a[o] = fmaxf(a[o], 0.f);

    float c[32];
    #pragma unroll
    for (int o = 0; o < 32; o++) c[o] = bo1[o];
    #pragma unroll
    for (int k = 0; k < 32; k++){
        float ak = a[k];
        const float* w = Wo1 + k*32;
        #pragma unroll
        for (int o = 0; o < 32; o++) c[o] = fmaf(ak, w[o], c[o]);
    }
    #pragma unroll
    for (int o = 0; o < 32; o++) c[o] = fmaxf(c[o], 0.f);

    float d[32];
    #pragma unroll
    for (int o = 0; o < 32; o++) d[o] = bo2[o];
    #pragma unroll
    for (int k = 0; k < 32; k++){
        float ck = c[k];
        const float* w = Wo2 + k*32;
        #pragma unroll
        for (int o = 0; o < 32; o++) d[o] = fmaf(ck, w[o], d[o]);
    }
    float s = bo3[0];
    #pragma unroll
    for (int k = 0; k < 32; k++) s = fmaf(fmaxf(d[k], 0.f), Wo3[k], s);
    out[n] = s;
}

extern "C" void kernel_launch(void* const* d_in, const int* in_sizes, int n_in,
                              void* d_out, int out_size, void* d_ws, size_t ws_size,
                              hipStream_t stream)
{
    (void)in_sizes; (void)n_in; (void)out_size; (void)ws_size;
    const float* consF = (const float*)d_in[0];
    const float* varsF = (const float*)d_in[1];
    const int*   eidx  = (const int*)d_in[2];
    const int*   eCons = eidx;
    const int*   eVars = eidx + E_N;

    const float* Wc  = (const float*)d_in[3],  *bc  = (const float*)d_in[4];
    const float* Wv  = (const float*)d_in[5],  *bv  = (const float*)d_in[6];
    const float* Wj1 = (const float*)d_in[7],  *bj1 = (const float*)d_in[8];
    const float* Wj2 = (const float*)d_in[9],  *bj2 = (const float*)d_in[10];
    const float* Wcr = (const float*)d_in[11], *bcr = (const float*)d_in[12];
    const float* Wvr = (const float*)d_in[13], *bvr = (const float*)d_in[14];
    const float* Wo1 = (const float*)d_in[15], *bo1 = (const float*)d_in[16];
    const float* Wo2 = (const float*)d_in[17], *bo2 = (const float*)d_in[18];
    const float* Wo3 = (const float*)d_in[19], *bo3 = (const float*)d_in[20];

    float* c_emb = (float*)d_ws;                    // [NC,32], becomes out_c in place
    float* v_emb = c_emb + (size_t)NC_N * 32;       // [NV,32]
    float* accum = v_emb + (size_t)NV_N * 32;       // [max(NC,NV),32], reused

    k_embed_cons<<<dim3(391), dim3(256), 0, stream>>>(consF, Wc, bc, c_emb);
    k_embed_vars<<<dim3(391), dim3(256), 0, stream>>>(varsF, Wv, bv, v_emb);

    hipMemsetAsync(accum, 0, (size_t)NC_N * 32 * 4, stream);
    k_edge<<<dim3(12500), dim3(256), 0, stream>>>(c_emb, v_emb, eCons, eVars,
                                                  Wj1, bj1, Wj2, bj2, accum, 0);
    k_consrep<<<dim3(391), dim3(256), 0, stream>>>(accum, c_emb, Wcr, bcr);

    hipMemsetAsync(accum, 0, (size_t)NV_N * 32 * 4, stream);
    k_edge<<<dim3(12500), dim3(256), 0, stream>>>(c_emb, v_emb, eCons, eVars,
                                                  Wj1, bj1, Wj2, bj2, accum, 1);
    k_out<<<dim3(391), dim3(256), 0, stream>>>(accum, v_emb, Wvr, bvr,
                                               Wo1, bo1, Wo2, bo2, Wo3, bo3,
                                               (float*)d_out);
}

// Round 3
// 2143.873 us; speedup vs baseline: 4.9463x; 4.9463x over previous
//
#include <hip/hip_runtime.h>

#define NC_N 100000
#define NV_N 100000
#define E_N  3200000

// ---------------- node embedding kernels ----------------

// c = relu(cons_features @ Wc + bc) : [NC,2] -> f32 table [NC,32]
__global__ __launch_bounds__(256) void k_embed_cons(
    const float* __restrict__ f, const float* __restrict__ W,
    const float* __restrict__ b, float* __restrict__ out)
{
    int n = blockIdx.x * blockDim.x + threadIdx.x;
    if (n >= NC_N) return;
    float f0 = f[2*(size_t)n], f1 = f[2*(size_t)n + 1];
    float4* dst = (float4*)(out + (size_t)n * 32);
    #pragma unroll
    for (int q = 0; q < 8; q++){
        float4 r;
        #pragma unroll
        for (int j = 0; j < 4; j++){
            int o = q*4 + j;
            (&r.x)[j] = fmaxf(fmaf(f0, W[o], fmaf(f1, W[32 + o], b[o])), 0.f);
        }
        dst[q] = r;
    }
}

// v = relu(vars_features @ Wv + bv) : [NV,9] -> f32 table [NV,32]
__global__ __launch_bounds__(256) void k_embed_vars(
    const float* __restrict__ f, const float* __restrict__ W,
    const float* __restrict__ b, float* __restrict__ out)
{
    int n = blockIdx.x * blockDim.x + threadIdx.x;
    if (n >= NV_N) return;
    float x[9];
    #pragma unroll
    for (int k = 0; k < 9; k++) x[k] = f[9*(size_t)n + k];
    float4* dst = (float4*)(out + (size_t)n * 32);
    #pragma unroll
    for (int q = 0; q < 8; q++){
        float4 r;
        #pragma unroll
        for (int j = 0; j < 4; j++){
            int o = q*4 + j;
            float s = b[o];
            #pragma unroll
            for (int k = 0; k < 9; k++) s = fmaf(x[k], W[k*32 + o], s);
            (&r.x)[j] = fmaxf(s, 0.f);
        }
        dst[q] = r;
    }
}

// out[N,32] = x[N,32] @ W[32,32] (+ bias, optional). No relu.
__global__ __launch_bounds__(256) void k_mm32(
    const float* __restrict__ x, const float* __restrict__ W,
    const float* __restrict__ bias, float* __restrict__ out, int n)
{
    int i = blockIdx.x * blockDim.x + threadIdx.x;
    if (i >= n) return;
    float h[32];
    if (bias){
        #pragma unroll
        for (int o = 0; o < 32; o++) h[o] = bias[o];
    } else {
        #pragma unroll
        for (int o = 0; o < 32; o++) h[o] = 0.f;
    }
    const float4* xp = (const float4*)(x + (size_t)i * 32);
    #pragma unroll
    for (int q = 0; q < 8; q++){
        float4 t = xp[q];
        #pragma unroll
        for (int j = 0; j < 4; j++){
            float xk = (&t.x)[j];
            const float* w = W + (q*4 + j)*32;
            #pragma unroll
            for (int o = 0; o < 32; o++) h[o] = fmaf(xk, w[o], h[o]);
        }
    }
    float4* dst = (float4*)(out + (size_t)i * 32);
    #pragma unroll
    for (int q = 0; q < 8; q++){
        float4 r;
        #pragma unroll
        for (int j = 0; j < 4; j++) (&r.x)[j] = h[q*4 + j];
        dst[q] = r;
    }
}

// P[n*32 + o] += b[o]  (turn pass-1 varying table into pass-2 const table)
__global__ __launch_bounds__(256) void k_badd(
    float* __restrict__ P, const float* __restrict__ b, int n)
{
    int i = blockIdx.x * blockDim.x + threadIdx.x;
    if (i >= n * 32) return;
    P[i] += b[i & 31];
}

// ---------------- CSR build ----------------

__global__ __launch_bounds__(256) void k_hist(
    const int* __restrict__ key, int* __restrict__ cnt)
{
    int e = blockIdx.x * blockDim.x + threadIdx.x;
    if (e >= E_N) return;
    atomicAdd(&cnt[key[e]], 1);
}

// per-block inclusive scan -> exclusive offsets + block sums
__global__ __launch_bounds__(256) void k_scan_block(
    const int* __restrict__ cnt, int* __restrict__ offs,
    int* __restrict__ bsum, int n)
{
    __shared__ int s[256];
    int i = blockIdx.x * 256 + threadIdx.x;
    int v = (i < n) ? cnt[i] : 0;
    s[threadIdx.x] = v;
    __syncthreads();
    #pragma unroll
    for (int d = 1; d < 256; d <<= 1){
        int t = (threadIdx.x >= d) ? s[threadIdx.x - d] : 0;
        __syncthreads();
        s[threadIdx.x] += t;
        __syncthreads();
    }
    if (i < n) offs[i] = s[threadIdx.x] - v;         // exclusive within block
    if (threadIdx.x == 255) bsum[blockIdx.x] = s[255];
}

// single block: exclusive scan of block sums (nb <= 512)
__global__ __launch_bounds__(512) void k_scan_top(int* __restrict__ bsum, int nb)
{
    __shared__ int s[512];
    int v = (threadIdx.x < nb) ? bsum[threadIdx.x] : 0;
    s[threadIdx.x] = v;
    __syncthreads();
    #pragma unroll
    for (int d = 1; d < 512; d <<= 1){
        int t = (threadIdx.x >= d) ? s[threadIdx.x - d] : 0;
        __syncthreads();
        s[threadIdx.x] += t;
        __syncthreads();
    }
    if (threadIdx.x < nb) bsum[threadIdx.x] = s[threadIdx.x] - v;
}

__global__ __launch_bounds__(256) void k_scan_add(
    int* __restrict__ offs, int* __restrict__ cursor,
    const int* __restrict__ bsum, int n)
{
    int i = blockIdx.x * 256 + threadIdx.x;
    if (i >= n) return;
    int o = offs[i] + bsum[blockIdx.x];
    offs[i] = o;
    cursor[i] = o;
}

// elist[pos] = other-endpoint of each edge, grouped by key
__global__ __launch_bounds__(256) void k_scatter(
    const int* __restrict__ key, const int* __restrict__ other,
    int* __restrict__ cursor, int* __restrict__ elist)
{
    int e = blockIdx.x * blockDim.x + threadIdx.x;
    if (e >= E_N) return;
    int k = key[e];
    int p = atomicAdd(&cursor[k], 1);
    elist[p] = other[e];
}

// ---------------- node-centric edge pass ----------------
// One 32-lane group per target node. Lane l owns output column l.
// h_e = relu(Pconst[node] + Pvar[other_e])          (layer 1, precomputed)
// g_e = relu(W2^T h_e + b2); acc += g_e             (layer 2 via shfl broadcast)
__global__ __launch_bounds__(256) void k_edge_csr(
    const float* __restrict__ Pconst, const float* __restrict__ Pvar,
    const int* __restrict__ offs, const int* __restrict__ cnt,
    const int* __restrict__ elist,
    const float* __restrict__ W2, const float* __restrict__ b2,
    float* __restrict__ accum, int n)
{
    int g = (blockIdx.x * blockDim.x + threadIdx.x) >> 5;
    int l = threadIdx.x & 31;
    if (g >= n) return;

    float w2c[32];                       // W2 column l, resident in VGPRs
    #pragma unroll
    for (int k = 0; k < 32; k++) w2c[k] = W2[k*32 + l];
    float b2l = b2[l];
    float cpart = Pconst[(size_t)g * 32 + l];

    int start = offs[g], deg = cnt[g];
    float acc = 0.f;
    for (int i = 0; i < deg; i++){
        int idx = elist[start + i];                    // broadcast load
        float p = Pvar[(size_t)idx * 32 + l];          // coalesced 128B/group
        float h = fmaxf(cpart + p, 0.f);
        float gg = b2l;
        #pragma unroll
        for (int k = 0; k < 32; k++){
            float hk = __shfl(h, k, 32);
            gg = fmaf(hk, w2c[k], gg);
        }
        acc += fmaxf(gg, 0.f);
    }
    accum[(size_t)g * 32 + l] = acc;
}

// ---------------- representation / output ----------------

// out_c = relu(concat(acc, c) @ Wcr + bcr), in place over c table
__global__ __launch_bounds__(256) void k_consrep(
    const float* __restrict__ acc, float* __restrict__ cemb,
    const float* __restrict__ W, const float* __restrict__ b)
{
    int n = blockIdx.x * blockDim.x + threadIdx.x;
    if (n >= NC_N) return;
    float h[32];
    #pragma unroll
    for (int o = 0; o < 32; o++) h[o] = b[o];
    const float4* ap = (const float4*)(acc + (size_t)n * 32);
    #pragma unroll
    for (int q = 0; q < 8; q++){
        float4 t = ap[q];
        #pragma unroll
        for (int j = 0; j < 4; j++){
            float xk = (&t.x)[j];
            const float* w = W + (q*4 + j)*32;
            #pragma unroll
            for (int o = 0; o < 32; o++) h[o] = fmaf(xk, w[o], h[o]);
        }
    }
    const float4* cp = (const float4*)(cemb + (size_t)n * 32);
    #pragma unroll
    for (int q = 0; q < 8; q++){
        float4 t = cp[q];
        #pragma unroll
        for (int j = 0; j < 4; j++){
            float xk = (&t.x)[j];
            const float* w = W + (32 + q*4 + j)*32;
            #pragma unroll
            for (int o = 0; o < 32; o++) h[o] = fmaf(xk, w[o], h[o]);
        }
    }
    float4* dst = (float4*)(cemb + (size_t)n * 32);
    #pragma unroll
    for (int q = 0; q < 8; q++){
        float4 r;
        #pragma unroll
        for (int j = 0; j < 4; j++) (&r.x)[j] = fmaxf(h[q*4 + j], 0.f);
        dst[q] = r;
    }
}

// out_v = relu(concat(acc, v)@Wvr+bvr); relu(@Wo1); relu(@Wo2); @Wo3+bo3 -> [NV,1]
__global__ __launch_bounds__(256) void k_out(
    const float* __restrict__ acc, const float* __restrict__ vemb,
    const float* __restrict__ Wvr, const float* __restrict__ bvr,
    const float* __restrict__ Wo1, const float* __restrict__ bo1,
    const float* __restrict__ Wo2, const float* __restrict__ bo2,
    const float* __restrict__ Wo3, const float* __restrict__ bo3,
    float* __restrict__ out)
{
    int n = blockIdx.x * blockDim.x + threadIdx.x;
    if (n >= NV_N) return;
    float a[32];
    #pragma unroll
    for (int o = 0; o < 32; o++) a[o] = bvr[o];
    const float4* ap = (const float4*)(acc + (size_t)n * 32);
    #pragma unroll
    for (int q = 0; q < 8; q++){
        float4 t = ap[q];
        #pragma unroll
        for (int j = 0; j < 4; j++){
            float xk = (&t.x)[j];
            const float* w = Wvr + (q*4 + j)*32;
            #pragma unroll
            for (int o = 0; o < 32; o++) a[o] = fmaf(xk, w[o], a[o]);
        }
    }
    const float4* vp = (const float4*)(vemb + (size_t)n * 32);
    #pragma unroll
    for (int q = 0; q < 8; q++){
        float4 t = vp[q];
        #pragma unroll
        for (int j = 0; j < 4; j++){
            float xk = (&t.x)[j];
            const float* w = Wvr + (32 + q*4 + j)*32;
            #pragma unroll
            for (int o = 0; o < 32; o++) a[o] = fmaf(xk, w[o], a[o]);
        }
    }
    #pragma unroll
    for (int o = 0; o < 32; o++) a[o] = fmaxf(a[o], 0.f);

    float c[32];
    #pragma unroll
    for (int o = 0; o < 32; o++) c[o] = bo1[o];
    #pragma unroll
    for (int k = 0; k < 32; k++){
        float ak = a[k];
        const float* w = Wo1 + k*32;
        #pragma unroll
        for (int o = 0; o < 32; o++) c[o] = fmaf(ak, w[o], c[o]);
    }
    #pragma unroll
    for (int o = 0; o < 32; o++) c[o] = fmaxf(c[o], 0.f);

    float d[32];
    #pragma unroll
    for (int o = 0; o < 32; o++) d[o] = bo2[o];
    #pragma unroll
    for (int k = 0; k < 32; k++){
        float ck = c[k];
        const float* w = Wo2 + k*32;
        #pragma unroll
        for (int o = 0; o < 32; o++) d[o] = fmaf(ck, w[o], d[o]);
    }
    float s = bo3[0];
    #pragma unroll
    for (int k = 0; k < 32; k++) s = fmaf(fmaxf(d[k], 0.f), Wo3[k], s);
    out[n] = s;
}

// ---------------- launch ----------------

static inline void build_csr(const int* key, const int* other,
                             int* cnt, int* offs, int* cursor, int* bsum,
                             int* elist, int n, hipStream_t stream)
{
    int nb = (n + 255) / 256;   // 391 for 100k
    hipMemsetAsync(cnt, 0, (size_t)n * 4, stream);
    k_hist<<<dim3(12500), dim3(256), 0, stream>>>(key, cnt);
    k_scan_block<<<dim3(nb), dim3(256), 0, stream>>>(cnt, offs, bsum, n);
    k_scan_top<<<dim3(1), dim3(512), 0, stream>>>(bsum, nb);
    k_scan_add<<<dim3(nb), dim3(256), 0, stream>>>(offs, cursor, bsum, n);
    k_scatter<<<dim3(12500), dim3(256), 0, stream>>>(key, other, cursor, elist);
}

extern "C" void kernel_launch(void* const* d_in, const int* in_sizes, int n_in,
                              void* d_out, int out_size, void* d_ws, size_t ws_size,
                              hipStream_t stream)
{
    (void)in_sizes; (void)n_in; (void)out_size; (void)ws_size;
    const float* consF = (const float*)d_in[0];
    const float* varsF = (const float*)d_in[1];
    const int*   eidx  = (const int*)d_in[2];
    const int*   eCons = eidx;
    const int*   eVars = eidx + E_N;

    const float* Wc  = (const float*)d_in[3],  *bc  = (const float*)d_in[4];
    const float* Wv  = (const float*)d_in[5],  *bv  = (const float*)d_in[6];
    const float* Wj1 = (const float*)d_in[7],  *bj1 = (const float*)d_in[8];
    const float* Wj2 = (const float*)d_in[9],  *bj2 = (const float*)d_in[10];
    const float* Wcr = (const float*)d_in[11], *bcr = (const float*)d_in[12];
    const float* Wvr = (const float*)d_in[13], *bvr = (const float*)d_in[14];
    const float* Wo1 = (const float*)d_in[15], *bo1 = (const float*)d_in[16];
    const float* Wo2 = (const float*)d_in[17], *bo2 = (const float*)d_in[18];
    const float* Wo3 = (const float*)d_in[19], *bo3 = (const float*)d_in[20];

    const size_t NT = (size_t)100000 * 32;         // one node table
    float* c_emb = (float*)d_ws;                   // [NC,32] -> out_c in place
    float* v_emb = c_emb + NT;                     // [NV,32]
    float* P1    = v_emb + NT;                     // v@W1v  (pass1 var / pass2 const)
    float* P2    = P1 + NT;                        // c@W1c+b1 (pass1 const) / outc@W1c (pass2 var)
    float* accum = P2 + NT;                        // [N,32] segment sums
    int*   cnt    = (int*)(accum + NT);            // [100k]
    int*   offs   = cnt + 100000;
    int*   cursor = offs + 100000;
    int*   bsum   = cursor + 100000;               // [512]
    int*   elist  = bsum + 512;                    // [E]

    const float* W1c = Wj1;                        // rows 0..31  (a/cons side)
    const float* W1v = Wj1 + 32*32;                // rows 32..63 (vars side)

    k_embed_cons<<<dim3(391), dim3(256), 0, stream>>>(consF, Wc, bc, c_emb);
    k_embed_vars<<<dim3(391), dim3(256), 0, stream>>>(varsF, Wv, bv, v_emb);
    k_mm32<<<dim3(391), dim3(256), 0, stream>>>(v_emb, W1v, nullptr, P1, NV_N);
    k_mm32<<<dim3(391), dim3(256), 0, stream>>>(c_emb, W1c, bj1, P2, NC_N);

    // ---- pass 1: edges -> constraints ----
    build_csr(eCons, eVars, cnt, offs, cursor, bsum, elist, NC_N, stream);
    k_edge_csr<<<dim3(12500), dim3(256), 0, stream>>>(P2, P1, offs, cnt, elist,
                                                      Wj2, bj2, accum, NC_N);
    k_consrep<<<dim3(391), dim3(256), 0, stream>>>(accum, c_emb, Wcr, bcr);

    // ---- pass 2: edges -> variables ----
    k_mm32<<<dim3(391), dim3(256), 0, stream>>>(c_emb, W1c, nullptr, P2, NC_N);
    k_badd<<<dim3(12500), dim3(256), 0, stream>>>(P1, bj1, NV_N);
    build_csr(eVars, eCons, cnt, offs, cursor, bsum, elist, NV_N, stream);
    k_edge_csr<<<dim3(12500), dim3(256), 0, stream>>>(P1, P2, offs, cnt, elist,
                                                      Wj2, bj2, accum, NV_N);
    k_out<<<dim3(391), dim3(256), 0, stream>>>(accum, v_emb, Wvr, bvr,
                                               Wo1, bo1, Wo2, bo2, Wo3, bo3,
                                               (float*)d_out);
}

// Round 4
// 1181.788 us; speedup vs baseline: 8.9731x; 1.8141x over previous
//
#include <hip/hip_runtime.h>

#define NC_N 100000
#define NV_N 100000
#define E_N  3200000

typedef __attribute__((ext_vector_type(8))) __bf16 bf16x8;
typedef __attribute__((ext_vector_type(4))) float  f32x4;

// ---------------- node embedding kernels ----------------

__global__ __launch_bounds__(256) void k_embed_cons(
    const float* __restrict__ f, const float* __restrict__ W,
    const float* __restrict__ b, float* __restrict__ out)
{
    int n = blockIdx.x * blockDim.x + threadIdx.x;
    if (n >= NC_N) return;
    float f0 = f[2*(size_t)n], f1 = f[2*(size_t)n + 1];
    float4* dst = (float4*)(out + (size_t)n * 32);
    #pragma unroll
    for (int q = 0; q < 8; q++){
        float4 r;
        #pragma unroll
        for (int j = 0; j < 4; j++){
            int o = q*4 + j;
            (&r.x)[j] = fmaxf(fmaf(f0, W[o], fmaf(f1, W[32 + o], b[o])), 0.f);
        }
        dst[q] = r;
    }
}

__global__ __launch_bounds__(256) void k_embed_vars(
    const float* __restrict__ f, const float* __restrict__ W,
    const float* __restrict__ b, float* __restrict__ out)
{
    int n = blockIdx.x * blockDim.x + threadIdx.x;
    if (n >= NV_N) return;
    float x[9];
    #pragma unroll
    for (int k = 0; k < 9; k++) x[k] = f[9*(size_t)n + k];
    float4* dst = (float4*)(out + (size_t)n * 32);
    #pragma unroll
    for (int q = 0; q < 8; q++){
        float4 r;
        #pragma unroll
        for (int j = 0; j < 4; j++){
            int o = q*4 + j;
            float s = b[o];
            #pragma unroll
            for (int k = 0; k < 9; k++) s = fmaf(x[k], W[k*32 + o], s);
            (&r.x)[j] = fmaxf(s, 0.f);
        }
        dst[q] = r;
    }
}

// out[N,32] = x[N,32] @ W[32,32] (+ bias, optional). No relu.
__global__ __launch_bounds__(256) void k_mm32(
    const float* __restrict__ x, const float* __restrict__ W,
    const float* __restrict__ bias, float* __restrict__ out, int n)
{
    int i = blockIdx.x * blockDim.x + threadIdx.x;
    if (i >= n) return;
    float h[32];
    if (bias){
        #pragma unroll
        for (int o = 0; o < 32; o++) h[o] = bias[o];
    } else {
        #pragma unroll
        for (int o = 0; o < 32; o++) h[o] = 0.f;
    }
    const float4* xp = (const float4*)(x + (size_t)i * 32);
    #pragma unroll
    for (int q = 0; q < 8; q++){
        float4 t = xp[q];
        #pragma unroll
        for (int j = 0; j < 4; j++){
            float xk = (&t.x)[j];
            const float* w = W + (q*4 + j)*32;
            #pragma unroll
            for (int o = 0; o < 32; o++) h[o] = fmaf(xk, w[o], h[o]);
        }
    }
    float4* dst = (float4*)(out + (size_t)i * 32);
    #pragma unroll
    for (int q = 0; q < 8; q++){
        float4 r;
        #pragma unroll
        for (int j = 0; j < 4; j++) (&r.x)[j] = h[q*4 + j];
        dst[q] = r;
    }
}

__global__ __launch_bounds__(256) void k_badd(
    float* __restrict__ P, const float* __restrict__ b, int n)
{
    int i = blockIdx.x * blockDim.x + threadIdx.x;
    if (i >= n * 32) return;
    P[i] += b[i & 31];
}

// ---------------- combined CSR build (both directions at once) ----------------
// cnt/offs/cursor are length NC_N+NV_N: [0,NC) keyed by cons, [NC,NC+NV) by vars.
// One global scan => vars-section offsets live in [E, 2E) of the shared elist.

__global__ __launch_bounds__(256) void k_hist2(
    const int* __restrict__ eC, const int* __restrict__ eV, int* __restrict__ cnt)
{
    int e = blockIdx.x * blockDim.x + threadIdx.x;
    if (e >= E_N) return;
    atomicAdd(&cnt[eC[e]], 1);
    atomicAdd(&cnt[NC_N + eV[e]], 1);
}

__global__ __launch_bounds__(256) void k_scan_block(
    const int* __restrict__ cnt, int* __restrict__ offs,
    int* __restrict__ bsum, int n)
{
    __shared__ int s[256];
    int i = blockIdx.x * 256 + threadIdx.x;
    int v = (i < n) ? cnt[i] : 0;
    s[threadIdx.x] = v;
    __syncthreads();
    #pragma unroll
    for (int d = 1; d < 256; d <<= 1){
        int t = (threadIdx.x >= d) ? s[threadIdx.x - d] : 0;
        __syncthreads();
        s[threadIdx.x] += t;
        __syncthreads();
    }
    if (i < n) offs[i] = s[threadIdx.x] - v;
    if (threadIdx.x == 255) bsum[blockIdx.x] = s[255];
}

// single block: exclusive scan of block sums (nb <= 1024)
__global__ __launch_bounds__(1024) void k_scan_top(int* __restrict__ bsum, int nb)
{
    __shared__ int s[1024];
    int v = (threadIdx.x < nb) ? bsum[threadIdx.x] : 0;
    s[threadIdx.x] = v;
    __syncthreads();
    #pragma unroll
    for (int d = 1; d < 1024; d <<= 1){
        int t = (threadIdx.x >= d) ? s[threadIdx.x - d] : 0;
        __syncthreads();
        s[threadIdx.x] += t;
        __syncthreads();
    }
    if (threadIdx.x < nb) bsum[threadIdx.x] = s[threadIdx.x] - v;
}

__global__ __launch_bounds__(256) void k_scan_add(
    int* __restrict__ offs, int* __restrict__ cursor,
    const int* __restrict__ bsum, int n)
{
    int i = blockIdx.x * 256 + threadIdx.x;
    if (i >= n) return;
    int o = offs[i] + bsum[blockIdx.x];
    offs[i] = o;
    cursor[i] = o;
}

__global__ __launch_bounds__(256) void k_scatter2(
    const int* __restrict__ eC, const int* __restrict__ eV,
    int* __restrict__ cursor, int* __restrict__ elist)
{
    int e = blockIdx.x * blockDim.x + threadIdx.x;
    if (e >= E_N) return;
    int kc = eC[e], kv = eV[e];
    int p1 = atomicAdd(&cursor[kc], 1);
    elist[p1] = kv;
    int p2 = atomicAdd(&cursor[NC_N + kv], 1);
    elist[p2] = kc;
}

// ---------------- W2 fragment prep (hi/lo bf16 split, MFMA B-layout) ----------
// w2hi/w2lo: [2 halves][64 lanes][8] bf16.  lane l, elem j -> W2[(l>>4)*8+j][h*16+(l&15)]
__global__ __launch_bounds__(128) void k_w2prep(
    const float* __restrict__ W2, __bf16* __restrict__ w2hi, __bf16* __restrict__ w2lo)
{
    int t = threadIdx.x;
    if (t >= 128) return;
    int h = t >> 6, l = t & 63;
    bf16x8 vh, vl;
    #pragma unroll
    for (int j = 0; j < 8; j++){
        float w = W2[((l >> 4) * 8 + j) * 32 + h * 16 + (l & 15)];
        __bf16 hi = (__bf16)w;
        vh[j] = hi;
        vl[j] = (__bf16)(w - (float)hi);
    }
    ((bf16x8*)w2hi)[t] = vh;
    ((bf16x8*)w2lo)[t] = vl;
}

// ---------------- MFMA edge pass: one wave per target node -------------------
// h_e = relu(Pconst[node] + Pvar[other_e])  (layer-1 hoisted, f32)
// G-tile = H(16x32) @ W2(32x32) via 16x16x32 bf16 MFMA, hi/lo split (fp32-class).
// acc[node][col] = sum_e relu(G[e][col] + b2[col]); tail rows predicated off.
__global__ __launch_bounds__(256) void k_edge_mfma(
    const float* __restrict__ Pconst, const float* __restrict__ Pvar,
    const int* __restrict__ offs, const int* __restrict__ cnt,
    const int* __restrict__ elist,
    const __bf16* __restrict__ w2hi, const __bf16* __restrict__ w2lo,
    const float* __restrict__ b2, float* __restrict__ accum, int n)
{
    int wid = (blockIdx.x * 256 + threadIdx.x) >> 6;
    int l   = threadIdx.x & 63;
    if (wid >= n) return;
    int row = l & 15;     // A-row (edge within tile) / C-col
    int kg  = l >> 4;     // k-chunk group

    bf16x8 wh0 = ((const bf16x8*)w2hi)[l];
    bf16x8 wh1 = ((const bf16x8*)w2hi)[64 + l];
    bf16x8 wl0 = ((const bf16x8*)w2lo)[l];
    bf16x8 wl1 = ((const bf16x8*)w2lo)[64 + l];
    float b2a = b2[row];
    float b2b = b2[16 + row];

    const float* pc = Pconst + (size_t)wid * 32 + kg * 8;
    f32x4 pc0 = *(const f32x4*)pc;
    f32x4 pc1 = *(const f32x4*)(pc + 4);

    int start = offs[wid], deg = cnt[wid];
    float acc0 = 0.f, acc1 = 0.f;
    int ntile = (deg + 15) >> 4;

    for (int t = 0; t < ntile; t++){
        int r  = t * 16 + row;
        int rc = (r < deg) ? r : (deg - 1);
        int other = elist[start + rc];
        const float* pv = Pvar + (size_t)other * 32 + kg * 8;
        f32x4 a0 = *(const f32x4*)pv;
        f32x4 a1 = *(const f32x4*)(pv + 4);

        bf16x8 ahi, alo;
        #pragma unroll
        for (int j = 0; j < 4; j++){
            float h0 = fmaxf(pc0[j] + a0[j], 0.f);
            float h1 = fmaxf(pc1[j] + a1[j], 0.f);
            __bf16 H0 = (__bf16)h0;
            __bf16 H1 = (__bf16)h1;
            ahi[j]     = H0;  alo[j]     = (__bf16)(h0 - (float)H0);
            ahi[4 + j] = H1;  alo[4 + j] = (__bf16)(h1 - (float)H1);
        }

        f32x4 c0 = {0.f, 0.f, 0.f, 0.f}, c1 = {0.f, 0.f, 0.f, 0.f};
        c0 = __builtin_amdgcn_mfma_f32_16x16x32_bf16(ahi, wh0, c0, 0, 0, 0);
        c0 = __builtin_amdgcn_mfma_f32_16x16x32_bf16(ahi, wl0, c0, 0, 0, 0);
        c0 = __builtin_amdgcn_mfma_f32_16x16x32_bf16(alo, wh0, c0, 0, 0, 0);
        c1 = __builtin_amdgcn_mfma_f32_16x16x32_bf16(ahi, wh1, c1, 0, 0, 0);
        c1 = __builtin_amdgcn_mfma_f32_16x16x32_bf16(ahi, wl1, c1, 0, 0, 0);
        c1 = __builtin_amdgcn_mfma_f32_16x16x32_bf16(alo, wh1, c1, 0, 0, 0);

        #pragma unroll
        for (int rr = 0; rr < 4; rr++){
            int er = t * 16 + kg * 4 + rr;   // C row = edge index
            if (er < deg){
                acc0 += fmaxf(c0[rr] + b2a, 0.f);
                acc1 += fmaxf(c1[rr] + b2b, 0.f);
            }
        }
    }

    // sum across the 4 row-groups (lanes l, l^16, l^32, l^48)
    acc0 += __shfl_xor(acc0, 16, 64);
    acc0 += __shfl_xor(acc0, 32, 64);
    acc1 += __shfl_xor(acc1, 16, 64);
    acc1 += __shfl_xor(acc1, 32, 64);

    if (l < 16)      accum[(size_t)wid * 32 + l] = acc0;       // cols 0..15
    else if (l < 32) accum[(size_t)wid * 32 + l] = acc1;       // cols 16..31
}

// ---------------- representation / output ----------------

__global__ __launch_bounds__(256) void k_consrep(
    const float* __restrict__ acc, float* __restrict__ cemb,
    const float* __restrict__ W, const float* __restrict__ b)
{
    int n = blockIdx.x * blockDim.x + threadIdx.x;
    if (n >= NC_N) return;
    float h[32];
    #pragma unroll
    for (int o = 0; o < 32; o++) h[o] = b[o];
    const float4* ap = (const float4*)(acc + (size_t)n * 32);
    #pragma unroll
    for (int q = 0; q < 8; q++){
        float4 t = ap[q];
        #pragma unroll
        for (int j = 0; j < 4; j++){
            float xk = (&t.x)[j];
            const float* w = W + (q*4 + j)*32;
            #pragma unroll
            for (int o = 0; o < 32; o++) h[o] = fmaf(xk, w[o], h[o]);
        }
    }
    const float4* cp = (const float4*)(cemb + (size_t)n * 32);
    #pragma unroll
    for (int q = 0; q < 8; q++){
        float4 t = cp[q];
        #pragma unroll
        for (int j = 0; j < 4; j++){
            float xk = (&t.x)[j];
            const float* w = W + (32 + q*4 + j)*32;
            #pragma unroll
            for (int o = 0; o < 32; o++) h[o] = fmaf(xk, w[o], h[o]);
        }
    }
    float4* dst = (float4*)(cemb + (size_t)n * 32);
    #pragma unroll
    for (int q = 0; q < 8; q++){
        float4 r;
        #pragma unroll
        for (int j = 0; j < 4; j++) (&r.x)[j] = fmaxf(h[q*4 + j], 0.f);
        dst[q] = r;
    }
}

__global__ __launch_bounds__(256) void k_out(
    const float* __restrict__ acc, const float* __restrict__ vemb,
    const float* __restrict__ Wvr, const float* __restrict__ bvr,
    const float* __restrict__ Wo1, const float* __restrict__ bo1,
    const float* __restrict__ Wo2, const float* __restrict__ bo2,
    const float* __restrict__ Wo3, const float* __restrict__ bo3,
    float* __restrict__ out)
{
    int n = blockIdx.x * blockDim.x + threadIdx.x;
    if (n >= NV_N) return;
    float a[32];
    #pragma unroll
    for (int o = 0; o < 32; o++) a[o] = bvr[o];
    const float4* ap = (const float4*)(acc + (size_t)n * 32);
    #pragma unroll
    for (int q = 0; q < 8; q++){
        float4 t = ap[q];
        #pragma unroll
        for (int j = 0; j < 4; j++){
            float xk = (&t.x)[j];
            const float* w = Wvr + (q*4 + j)*32;
            #pragma unroll
            for (int o = 0; o < 32; o++) a[o] = fmaf(xk, w[o], a[o]);
        }
    }
    const float4* vp = (const float4*)(vemb + (size_t)n * 32);
    #pragma unroll
    for (int q = 0; q < 8; q++){
        float4 t = vp[q];
        #pragma unroll
        for (int j = 0; j < 4; j++){
            float xk = (&t.x)[j];
            const float* w = Wvr + (32 + q*4 + j)*32;
            #pragma unroll
            for (int o = 0; o < 32; o++) a[o] = fmaf(xk, w[o], a[o]);
        }
    }
    #pragma unroll
    for (int o = 0; o < 32; o++) a[o] = fmaxf(a[o], 0.f);

    float c[32];
    #pragma unroll
    for (int o = 0; o < 32; o++) c[o] = bo1[o];
    #pragma unroll
    for (int k = 0; k < 32; k++){
        float ak = a[k];
        const float* w = Wo1 + k*32;
        #pragma unroll
        for (int o = 0; o < 32; o++) c[o] = fmaf(ak, w[o], c[o]);
    }
    #pragma unroll
    for (int o = 0; o < 32; o++) c[o] = fmaxf(c[o], 0.f);

    float d[32];
    #pragma unroll
    for (int o = 0; o < 32; o++) d[o] = bo2[o];
    #pragma unroll
    for (int k = 0; k < 32; k++){
        float ck = c[k];
        const float* w = Wo2 + k*32;
        #pragma unroll
        for (int o = 0; o < 32; o++) d[o] = fmaf(ck, w[o], d[o]);
    }
    float s = bo3[0];
    #pragma unroll
    for (int k = 0; k < 32; k++) s = fmaf(fmaxf(d[k], 0.f), Wo3[k], s);
    out[n] = s;
}

// ---------------- launch ----------------

extern "C" void kernel_launch(void* const* d_in, const int* in_sizes, int n_in,
                              void* d_out, int out_size, void* d_ws, size_t ws_size,
                              hipStream_t stream)
{
    (void)in_sizes; (void)n_in; (void)out_size; (void)ws_size;
    const float* consF = (const float*)d_in[0];
    const float* varsF = (const float*)d_in[1];
    const int*   eidx  = (const int*)d_in[2];
    const int*   eCons = eidx;
    const int*   eVars = eidx + E_N;

    const float* Wc  = (const float*)d_in[3],  *bc  = (const float*)d_in[4];
    const float* Wv  = (const float*)d_in[5],  *bv  = (const float*)d_in[6];
    const float* Wj1 = (const float*)d_in[7],  *bj1 = (const float*)d_in[8];
    const float* Wj2 = (const float*)d_in[9],  *bj2 = (const float*)d_in[10];
    const float* Wcr = (const float*)d_in[11], *bcr = (const float*)d_in[12];
    const float* Wvr = (const float*)d_in[13], *bvr = (const float*)d_in[14];
    const float* Wo1 = (const float*)d_in[15], *bo1 = (const float*)d_in[16];
    const float* Wo2 = (const float*)d_in[17], *bo2 = (const float*)d_in[18];
    const float* Wo3 = (const float*)d_in[19], *bo3 = (const float*)d_in[20];

    const size_t NT = (size_t)100000 * 32;
    float* c_emb = (float*)d_ws;            // [NC,32] -> out_c in place
    float* v_emb = c_emb + NT;              // [NV,32]
    float* P1    = v_emb + NT;              // v@W1v (pass1 var side / pass2 const side)
    float* P2    = P1 + NT;                 // c@W1c+b1 (pass1 const) / outc@W1c (pass2 var)
    float* accum = P2 + NT;                 // [N,32] segment sums
    int*   cnt    = (int*)(accum + NT);     // [NC+NV]
    int*   offs   = cnt + 200000;           // [NC+NV]
    int*   cursor = offs + 200000;          // [NC+NV]
    int*   bsum   = cursor + 200000;        // [1024]
    int*   elist  = bsum + 1024;            // [2E]: [0,E) cons-keyed, [E,2E) vars-keyed
    __bf16* w2hi  = (__bf16*)(elist + 2*E_N);  // [2][64][8]
    __bf16* w2lo  = w2hi + 1024;

    const float* W1c = Wj1;                 // rows 0..31  (cons/out_c side)
    const float* W1v = Wj1 + 32*32;         // rows 32..63 (vars side)
    const int NTOT = NC_N + NV_N;
    const int NB   = (NTOT + 255) / 256;    // 782

    // --- CSR build for BOTH directions (input-only, done once) ---
    hipMemsetAsync(cnt, 0, (size_t)NTOT * 4, stream);
    k_hist2<<<dim3(12500), dim3(256), 0, stream>>>(eCons, eVars, cnt);
    k_scan_block<<<dim3(NB), dim3(256), 0, stream>>>(cnt, offs, bsum, NTOT);
    k_scan_top<<<dim3(1), dim3(1024), 0, stream>>>(bsum, NB);
    k_scan_add<<<dim3(NB), dim3(256), 0, stream>>>(offs, cursor, bsum, NTOT);
    k_scatter2<<<dim3(12500), dim3(256), 0, stream>>>(eCons, eVars, cursor, elist);
    k_w2prep<<<dim3(1), dim3(128), 0, stream>>>(Wj2, w2hi, w2lo);

    // --- embeddings + layer-1 hoist ---
    k_embed_cons<<<dim3(391), dim3(256), 0, stream>>>(consF, Wc, bc, c_emb);
    k_embed_vars<<<dim3(391), dim3(256), 0, stream>>>(varsF, Wv, bv, v_emb);
    k_mm32<<<dim3(391), dim3(256), 0, stream>>>(v_emb, W1v, nullptr, P1, NV_N);
    k_mm32<<<dim3(391), dim3(256), 0, stream>>>(c_emb, W1c, bj1, P2, NC_N);

    // ---- pass 1: edges -> constraints (keyed by cons; other = vars) ----
    k_edge_mfma<<<dim3(25000), dim3(256), 0, stream>>>(
        P2, P1, offs, cnt, elist, w2hi, w2lo, bj2, accum, NC_N);
    k_consrep<<<dim3(391), dim3(256), 0, stream>>>(accum, c_emb, Wcr, bcr);

    // ---- pass 2: edges -> variables (keyed by vars; other = cons) ----
    k_mm32<<<dim3(391), dim3(256), 0, stream>>>(c_emb, W1c, nullptr, P2, NC_N);
    k_badd<<<dim3(12500), dim3(256), 0, stream>>>(P1, bj1, NV_N);
    k_edge_mfma<<<dim3(25000), dim3(256), 0, stream>>>(
        P1, P2, offs + NC_N, cnt + NC_N, elist, w2hi, w2lo, bj2, accum, NV_N);
    k_out<<<dim3(391), dim3(256), 0, stream>>>(accum, v_emb, Wvr, bvr,
                                               Wo1, bo1, Wo2, bo2, Wo3, bo3,
                                               (float*)d_out);
}